// Round 13
// baseline (334.690 us; speedup 1.0000x reference)
//
#include <hip/hip_runtime.h>
#include <math.h>

#define N_NODES 50000
#define N_EDGES 800000
#define HD 256      // H*D
#define NHEAD 4
#define DH 64
#define NPAD 50048

#define GEMM_BLKS 782   // ceil(50000/64)
#define PACK_BLKS 96    // 384 tiles / 4 waves
#define HIST_BLKS 1563  // ceil(800000/2/256)
#define NB 49           // ceil(50000/1024)

typedef short bf16x8 __attribute__((ext_vector_type(8)));
typedef float f32x4 __attribute__((ext_vector_type(4)));

__device__ __forceinline__ unsigned short f2bf(float f) {  // RNE
    unsigned u = __float_as_uint(f);
    return (unsigned short)((u + 0x7fffu + ((u >> 16) & 1u)) >> 16);
}
__device__ __forceinline__ float bf2f(unsigned short h) {
    return __uint_as_float((unsigned)h << 16);
}
// π: stored col c' holds original col orig(c') = (c'&~63) | ((c'&3)*16 + ((c'>>2)&15))
__device__ __forceinline__ int origk(int k) {
    return (k & ~63) | ((k & 3) * 16 + ((k >> 2) & 15));
}

// ---------- shared GEMM pieces ----------
__device__ __forceinline__ void mfma_tile(const unsigned short* Asl,
                                          const unsigned short* wbase,
                                          int lane, f32x4 acc[4][4]) {
#pragma unroll
    for (int kk = 0; kk < 8; kk++) {
        bf16x8 a[4], b[4];
#pragma unroll
        for (int m = 0; m < 4; m++) {
            int r = m * 16 + (lane & 15);
            int kb = kk * 32 + (lane >> 4) * 8;
            int byt = (r * 512 + kb * 2) ^ ((r & 7) << 4);
            a[m] = *(const bf16x8*)((const char*)Asl + byt);
        }
#pragma unroll
        for (int n = 0; n < 4; n++)
            b[n] = *(const bf16x8*)(wbase + ((size_t)(n * 8 + kk) * 64 + lane) * 8);
#pragma unroll
        for (int m = 0; m < 4; m++)
#pragma unroll
            for (int n = 0; n < 4; n++)
                acc[m][n] = __builtin_amdgcn_mfma_f32_16x16x32_bf16(a[m], b[n],
                                                                    acc[m][n], 0, 0, 0);
    }
}

// el/er butterfly + π-layout C store (el bf16, er fp32)
__device__ __forceinline__ void epilogue_tile(f32x4 acc[4][4], int bm, int wv, int lane,
                                              const float* __restrict__ al,
                                              const float* __restrict__ ar,
                                              unsigned short* __restrict__ C,
                                              unsigned short* __restrict__ el,
                                              float* __restrict__ er, int M) {
    int rr = lane >> 4, cc = lane & 15;
    float alv[4], arv[4];
#pragma unroll
    for (int n = 0; n < 4; n++) {
        alv[n] = al[wv * 64 + n * 16 + cc];
        arv[n] = ar[wv * 64 + n * 16 + cc];
    }
    float vl[16], vr[16];
#pragma unroll
    for (int m = 0; m < 4; m++)
#pragma unroll
        for (int r = 0; r < 4; r++) {
            float ep = 0.f, rp = 0.f;
#pragma unroll
            for (int n = 0; n < 4; n++) {
                ep = fmaf(acc[m][n][r], alv[n], ep);
                rp = fmaf(acc[m][n][r], arv[n], rp);
            }
            vl[m * 4 + r] = ep;
            vr[m * 4 + r] = rp;
        }
    float l8[8], r8[8];
#pragma unroll
    for (int i = 0; i < 8; i++) {
        float xs = (cc & 1) ? vl[2 * i] : vl[2 * i + 1];
        float xk = (cc & 1) ? vl[2 * i + 1] : vl[2 * i];
        l8[i] = xk + __shfl_xor(xs, 1);
        float ys = (cc & 1) ? vr[2 * i] : vr[2 * i + 1];
        float yk = (cc & 1) ? vr[2 * i + 1] : vr[2 * i];
        r8[i] = yk + __shfl_xor(ys, 1);
    }
    float l4[4], r4[4];
#pragma unroll
    for (int i = 0; i < 4; i++) {
        float xs = (cc & 2) ? l8[2 * i] : l8[2 * i + 1];
        float xk = (cc & 2) ? l8[2 * i + 1] : l8[2 * i];
        l4[i] = xk + __shfl_xor(xs, 2);
        float ys = (cc & 2) ? r8[2 * i] : r8[2 * i + 1];
        float yk = (cc & 2) ? r8[2 * i + 1] : r8[2 * i];
        r4[i] = yk + __shfl_xor(ys, 2);
    }
    float l2[2], r2[2];
#pragma unroll
    for (int i = 0; i < 2; i++) {
        float xs = (cc & 4) ? l4[2 * i] : l4[2 * i + 1];
        float xk = (cc & 4) ? l4[2 * i + 1] : l4[2 * i];
        l2[i] = xk + __shfl_xor(xs, 4);
        float ys = (cc & 4) ? r4[2 * i] : r4[2 * i + 1];
        float yk = (cc & 4) ? r4[2 * i + 1] : r4[2 * i];
        r2[i] = yk + __shfl_xor(ys, 4);
    }
    {
        float xs = (cc & 8) ? l2[0] : l2[1];
        float xk = (cc & 8) ? l2[1] : l2[0];
        float lv = xk + __shfl_xor(xs, 8);
        float ys = (cc & 8) ? r2[0] : r2[1];
        float yk = (cc & 8) ? r2[1] : r2[0];
        float rv = yk + __shfl_xor(ys, 8);
        int row_e = bm + (cc >> 2) * 16 + rr * 4 + (cc & 3);
        if (row_e < M) {
            el[(size_t)row_e * NHEAD + wv] = f2bf(lv);
            er[(size_t)row_e * NHEAD + wv] = rv;
        }
    }
#pragma unroll
    for (int m = 0; m < 4; m++) {
#pragma unroll
        for (int r = 0; r < 4; r++) {
            int row = bm + m * 16 + rr * 4 + r;
            if (row < M) {
                unsigned short p4[4] = {f2bf(acc[m][0][r]), f2bf(acc[m][1][r]),
                                        f2bf(acc[m][2][r]), f2bf(acc[m][3][r])};
                *(ushort4*)(C + (size_t)row * 256 + wv * 64 + cc * 4) = *(ushort4*)p4;
            }
        }
    }
}

// ---------- dispatch A: packw ∥ hist (both depend only on kernel inputs) ----------
__global__ __launch_bounds__(256) void fused_ph_k(const float* __restrict__ W0,
                                                  const float* __restrict__ W1,
                                                  const float* __restrict__ W2,
                                                  unsigned short* __restrict__ Wp,
                                                  const int* __restrict__ dst,
                                                  int* __restrict__ deg) {
    int blk = blockIdx.x, tid = threadIdx.x, wv = tid >> 6, lane = tid & 63;
    if (blk < PACK_BLKS) {
        int tile = blk * 4 + wv;   // 0..383
        int L = tile >> 7, t = tile & 127;
        const float* W = L == 0 ? W0 : L == 1 ? W1 : W2;
        int nt = t >> 3, kt = t & 7;
        int col = nt * 16 + (lane & 15);
        int kb = kt * 32 + (lane >> 4) * 8;
        unsigned short v[8];
#pragma unroll
        for (int j = 0; j < 8; j++) {
            int k = kb + j;
            if (L > 0) k = origk(k);
            v[j] = f2bf(W[(size_t)k * 256 + col]);
        }
        *(bf16x8*)(Wp + ((size_t)(L * 128 + t) * 64 + lane) * 8) = *(bf16x8*)v;
    } else {
        int t = (blk - PACK_BLKS) * 256 + tid;
        int e = t * 2;
        int* mydeg = deg + (size_t)(tid & 3) * NPAD;
        if (e + 1 < N_EDGES) {
            int2 d2 = *(const int2*)(dst + e);
            atomicAdd(&mydeg[d2.x], 1);
            atomicAdd(&mydeg[d2.y], 1);
        } else if (e < N_EDGES) {
            atomicAdd(&mydeg[dst[e]], 1);
        }
    }
}

// ---------- dispatch B: layer-0 GEMM (reads Wp from dispatch A) ∥ scan1 (reads deg) ----------
__global__ __launch_bounds__(256) void fused_gs_k(const float* __restrict__ A,
                                                  const unsigned short* __restrict__ Wp,
                                                  const float* __restrict__ al,
                                                  const float* __restrict__ ar,
                                                  unsigned short* __restrict__ C,
                                                  unsigned short* __restrict__ el,
                                                  float* __restrict__ er,
                                                  const int* __restrict__ deg,
                                                  int* __restrict__ rowptr,
                                                  int* __restrict__ bsum, int M) {
    __shared__ unsigned short Asl[64 * 256];
    __shared__ int wsum2[4];
    int blk = blockIdx.x, tid = threadIdx.x, wv = tid >> 6, lane = tid & 63;
    if (blk < GEMM_BLKS) {
        int bm = blk * 64;
#pragma unroll
        for (int i = 0; i < 8; i++) {
            int chunk = i * 256 + tid;
            int r = chunk >> 5, kc = (chunk & 31) * 8;
            float4 f0, f1;
            if (bm + r < M) {
                const float* p = A + (size_t)(bm + r) * 256 + kc;
                f0 = *(const float4*)p;
                f1 = *(const float4*)(p + 4);
            } else {
                f0 = f1 = make_float4(0.f, 0.f, 0.f, 0.f);
            }
            unsigned short tmp[8] = {f2bf(f0.x), f2bf(f0.y), f2bf(f0.z), f2bf(f0.w),
                                     f2bf(f1.x), f2bf(f1.y), f2bf(f1.z), f2bf(f1.w)};
            int b = (r * 512 + kc * 2) ^ ((r & 7) << 4);
            *(bf16x8*)((char*)Asl + b) = *(bf16x8*)tmp;
        }
        __syncthreads();
        const unsigned short* wbase = Wp + (size_t)(wv * 4) * 8 * 64 * 8;
        f32x4 acc[4][4] = {};
        mfma_tile(Asl, wbase, lane, acc);
        epilogue_tile(acc, bm, wv, lane, al, ar, C, el, er, M);
    } else {
        // scan1: 256 threads × 4 elems = 1024 elems/block; local inclusive + bsum
        int sblk = blk - GEMM_BLKS;      // 0..NB-1
        int i0 = sblk * 1024 + tid * 4;
        int v[4], p[4];
#pragma unroll
        for (int j = 0; j < 4; j++) {
            int i = i0 + j;
            v[j] = (i < N_NODES)
                       ? deg[i] + deg[i + NPAD] + deg[i + 2 * NPAD] + deg[i + 3 * NPAD]
                       : 0;
        }
        p[0] = v[0]; p[1] = p[0] + v[1]; p[2] = p[1] + v[2]; p[3] = p[2] + v[3];
        int tot = p[3];
        int sc = tot;
#pragma unroll
        for (int o = 1; o < 64; o <<= 1) {
            int t = __shfl_up(sc, o);
            if (lane >= o) sc += t;
        }
        if (lane == 63) wsum2[wv] = sc;
        __syncthreads();
        int woff = 0;
#pragma unroll
        for (int w = 0; w < 4; w++)
            if (w < wv) woff += wsum2[w];
        int excl = woff + sc - tot;
#pragma unroll
        for (int j = 0; j < 4; j++) {
            int i = i0 + j;
            if (i < N_NODES) rowptr[i + 1] = excl + p[j];
        }
        if (tid == 255) bsum[sblk] = excl + p[3];   // block total
    }
}

// ---------- CSR scan finish + scatter ----------
__global__ __launch_bounds__(1024) void scan3_k(int* __restrict__ rowptr,
                                                const int* __restrict__ bsum,
                                                int* __restrict__ cursor, int nb) {
    __shared__ int boff_s;
    int tid = threadIdx.x;
    if (tid < 64) {
        int v = (tid < nb) ? bsum[tid] : 0;
        int sc = v;
#pragma unroll
        for (int o = 1; o < 64; o <<= 1) {
            int t = __shfl_up(sc, o);
            if ((tid & 63) >= o) sc += t;
        }
        if (tid == (int)blockIdx.x) boff_s = sc - v;  // exclusive prefix
    }
    __syncthreads();
    int off = boff_s;
    int i = blockIdx.x * 1024 + tid;
    if (blockIdx.x == 0 && tid == 0) { rowptr[0] = 0; cursor[0] = 0; }
    if (i < N_NODES) {
        int v = rowptr[i + 1] + off;
        rowptr[i + 1] = v;
        if (i + 1 < N_NODES) cursor[i + 1] = v;
    }
}

__global__ void scatter_k(const int* __restrict__ src, const int* __restrict__ dst,
                          int* __restrict__ cursor, int* __restrict__ csr_src) {
    int e = (blockIdx.x * 256 + threadIdx.x) * 2;
    if (e + 1 < N_EDGES) {
        int2 s2 = *(const int2*)(src + e);
        int2 d2 = *(const int2*)(dst + e);
        csr_src[atomicAdd(&cursor[d2.x], 1)] = s2.x;
        csr_src[atomicAdd(&cursor[d2.y], 1)] = s2.y;
    } else if (e < N_EDGES) {
        csr_src[atomicAdd(&cursor[dst[e]], 1)] = src[e];
    }
}

// ---------- layers 1/2 GEMM: bf16 A, 2 tiles/block, async dbuf (counted vmcnt) ----------
__global__ __launch_bounds__(256) void gemm2_k(const unsigned short* __restrict__ A,
                                               const unsigned short* __restrict__ Wp,
                                               const float* __restrict__ al,
                                               const float* __restrict__ ar,
                                               unsigned short* __restrict__ C,
                                               unsigned short* __restrict__ el,
                                               float* __restrict__ er, int M) {
    __shared__ unsigned short Asl[2][64 * 256];   // 64 KB
    int tid = threadIdx.x, wv = tid >> 6, lane = tid & 63;
    int bm0 = blockIdx.x * 128, bm1 = bm0 + 64;
#pragma unroll
    for (int i = 0; i < 8; i++) {
        int chunk = i * 256 + tid;
        int r = chunk >> 5;
        int c16 = (chunk & 31) ^ (r & 7);
        int grow = bm0 + r; if (grow >= M) grow = M - 1;
        __builtin_amdgcn_global_load_lds(
            (const __attribute__((address_space(1))) unsigned int*)
                (A + (size_t)grow * 256 + c16 * 8),
            (__attribute__((address_space(3))) unsigned int*)
                ((char*)Asl[0] + (size_t)chunk * 16),
            16, 0, 0);
    }
#pragma unroll
    for (int i = 0; i < 8; i++) {
        int chunk = i * 256 + tid;
        int r = chunk >> 5;
        int c16 = (chunk & 31) ^ (r & 7);
        int grow = bm1 + r; if (grow >= M) grow = M - 1;
        __builtin_amdgcn_global_load_lds(
            (const __attribute__((address_space(1))) unsigned int*)
                (A + (size_t)grow * 256 + c16 * 8),
            (__attribute__((address_space(3))) unsigned int*)
                ((char*)Asl[1] + (size_t)chunk * 16),
            16, 0, 0);
    }
    asm volatile("s_waitcnt vmcnt(8)" ::: "memory");   // tile0 landed; tile1 in flight
    __builtin_amdgcn_sched_barrier(0);
    __builtin_amdgcn_s_barrier();
    const unsigned short* wbase = Wp + (size_t)(wv * 4) * 8 * 64 * 8;
    f32x4 acc[4][4] = {};
    mfma_tile(Asl[0], wbase, lane, acc);
    asm volatile("s_waitcnt vmcnt(0)" ::: "memory");
    __builtin_amdgcn_sched_barrier(0);
    __builtin_amdgcn_s_barrier();
    epilogue_tile(acc, bm0, wv, lane, al, ar, C, el, er, M);
    f32x4 acc2[4][4] = {};
    mfma_tile(Asl[1], wbase, lane, acc2);
    epilogue_tile(acc2, bm1, wv, lane, al, ar, C, el, er, M);
}

// ---------- fused per-dst softmax (max-free) + gather-aggregate + epilogue ----------
// feat/resid/hb in π layout. el bf16. MODE 0: no resid, ELU; MODE 1: resid, ELU;
// MODE 2: resid, no act, head-mean, fp32 out (unpermuted)
template <int MODE>
__global__ __launch_bounds__(256) void agg_k(const int* __restrict__ rowptr,
                                             const int* __restrict__ csr_src,
                                             const unsigned short* __restrict__ el,
                                             const float* __restrict__ er,
                                             const unsigned short* __restrict__ feat,
                                             const unsigned short* __restrict__ resid,
                                             const float* __restrict__ bias,
                                             float* __restrict__ out,
                                             unsigned short* __restrict__ hb) {
    __shared__ int   ws_s[4][64];       // byte offsets s*512
    __shared__ float ws_w[4][4][68];    // [wave][head][edge], pad 68 de-banks
    int wv = threadIdx.x >> 6, lane = threadIdx.x & 63;
    int node = blockIdx.x * 4 + wv;
    if (node >= N_NODES) return;
    int beg = rowptr[node], end = rowptr[node + 1];
    float4 er4 = *(const float4*)(er + (size_t)node * 4);
    float4 acc0 = make_float4(0.f, 0.f, 0.f, 0.f);
    float4 acc1 = make_float4(0.f, 0.f, 0.f, 0.f);
    float4 den = make_float4(0.f, 0.f, 0.f, 0.f);
    int h = lane >> 4;
    int l8 = lane * 8;
    const char* fb = (const char*)feat;
    for (int base = beg; base < end; base += 64) {
        int j = base + lane;
        int soff = 0;
        float4 w = make_float4(0.f, 0.f, 0.f, 0.f);
        if (j < end) {
            int s = csr_src[j];
            soff = s << 9;              // byte offset of feat row (256 bf16)
            ushort4 l4u = *(const ushort4*)(el + (size_t)s * 4);
            float vx = bf2f(l4u.x) + er4.x; vx = vx > 0.f ? vx : 0.2f * vx;
            float vy = bf2f(l4u.y) + er4.y; vy = vy > 0.f ? vy : 0.2f * vy;
            float vz = bf2f(l4u.z) + er4.z; vz = vz > 0.f ? vz : 0.2f * vz;
            float vw = bf2f(l4u.w) + er4.w; vw = vw > 0.f ? vw : 0.2f * vw;
            // max-free softmax: |v| = O(3), exp cannot overflow fp32
            w.x = expf(vx); w.y = expf(vy); w.z = expf(vz); w.w = expf(vw);
            den.x += w.x; den.y += w.y; den.z += w.z; den.w += w.w;
        }
        ws_s[wv][lane] = soff;          // dummy lanes: soff=0, w=0
        ws_w[wv][0][lane] = w.x;
        ws_w[wv][1][lane] = w.y;
        ws_w[wv][2][lane] = w.z;
        ws_w[wv][3][lane] = w.w;
        __builtin_amdgcn_wave_barrier();
        int cnt = end - base; if (cnt > 64) cnt = 64;
        int cnt4 = (cnt + 3) & ~3;      // zero-padded: no tail loop
        for (int k = 0; k < cnt4; k += 4) {
            int4   so = *(const int4*)&ws_s[wv][k];      // broadcast
            float4 w4 = *(const float4*)&ws_w[wv][h][k];
            ushort4 u0 = *(const ushort4*)(fb + (so.x + l8));
            ushort4 u1 = *(const ushort4*)(fb + (so.y + l8));
            ushort4 u2 = *(const ushort4*)(fb + (so.z + l8));
            ushort4 u3 = *(const ushort4*)(fb + (so.w + l8));
            acc0.x = fmaf(w4.x, bf2f(u0.x), acc0.x);
            acc0.y = fmaf(w4.x, bf2f(u0.y), acc0.y);
            acc0.z = fmaf(w4.x, bf2f(u0.z), acc0.z);
            acc0.w = fmaf(w4.x, bf2f(u0.w), acc0.w);
            acc1.x = fmaf(w4.y, bf2f(u1.x), acc1.x);
            acc1.y = fmaf(w4.y, bf2f(u1.y), acc1.y);
            acc1.z = fmaf(w4.y, bf2f(u1.z), acc1.z);
            acc1.w = fmaf(w4.y, bf2f(u1.w), acc1.w);
            acc0.x = fmaf(w4.z, bf2f(u2.x), acc0.x);
            acc0.y = fmaf(w4.z, bf2f(u2.y), acc0.y);
            acc0.z = fmaf(w4.z, bf2f(u2.z), acc0.z);
            acc0.w = fmaf(w4.z, bf2f(u2.w), acc0.w);
            acc1.x = fmaf(w4.w, bf2f(u3.x), acc1.x);
            acc1.y = fmaf(w4.w, bf2f(u3.y), acc1.y);
            acc1.z = fmaf(w4.w, bf2f(u3.z), acc1.z);
            acc1.w = fmaf(w4.w, bf2f(u3.w), acc1.w);
        }
        __builtin_amdgcn_wave_barrier();
    }
    float4 acc;
    acc.x = acc0.x + acc1.x; acc.y = acc0.y + acc1.y;
    acc.z = acc0.z + acc1.z; acc.w = acc0.w + acc1.w;
#pragma unroll
    for (int o = 1; o < 64; o <<= 1) {
        den.x += __shfl_xor(den.x, o);
        den.y += __shfl_xor(den.y, o);
        den.z += __shfl_xor(den.z, o);
        den.w += __shfl_xor(den.w, o);
    }
    float den_me = h == 0 ? den.x : h == 1 ? den.y : h == 2 ? den.z : den.w;
    float r = den_me > 0.f ? 1.f / den_me : 0.f;
    int cc = lane & 15;
    float4 b4;
    b4.x = bias[h * 64 + 0 * 16 + cc];
    b4.y = bias[h * 64 + 1 * 16 + cc];
    b4.z = bias[h * 64 + 2 * 16 + cc];
    b4.w = bias[h * 64 + 3 * 16 + cc];
    float4 o4;
    o4.x = acc.x * r + b4.x;
    o4.y = acc.y * r + b4.y;
    o4.z = acc.z * r + b4.z;
    o4.w = acc.w * r + b4.w;
    if (MODE >= 1) {
        ushort4 r4 = *(const ushort4*)(resid + (size_t)node * HD + lane * 4);
        o4.x += bf2f(r4.x); o4.y += bf2f(r4.y);
        o4.z += bf2f(r4.z); o4.w += bf2f(r4.w);
    }
    if (MODE <= 1) {
        o4.x = o4.x > 0.f ? o4.x : expm1f(o4.x);
        o4.y = o4.y > 0.f ? o4.y : expm1f(o4.y);
        o4.z = o4.z > 0.f ? o4.z : expm1f(o4.z);
        o4.w = o4.w > 0.f ? o4.w : expm1f(o4.w);
        ushort4 hv;
        hv.x = f2bf(o4.x); hv.y = f2bf(o4.y); hv.z = f2bf(o4.z); hv.w = f2bf(o4.w);
        *(ushort4*)(hb + (size_t)node * HD + lane * 4) = hv;
    } else {
        o4.x += __shfl_xor(o4.x, 16); o4.x += __shfl_xor(o4.x, 32);
        o4.y += __shfl_xor(o4.y, 16); o4.y += __shfl_xor(o4.y, 32);
        o4.z += __shfl_xor(o4.z, 16); o4.z += __shfl_xor(o4.z, 32);
        o4.w += __shfl_xor(o4.w, 16); o4.w += __shfl_xor(o4.w, 32);
        if (lane < 16) {
            float* po = out + (size_t)node * DH;
            po[0 * 16 + lane] = o4.x * 0.25f;
            po[1 * 16 + lane] = o4.y * 0.25f;
            po[2 * 16 + lane] = o4.z * 0.25f;
            po[3 * 16 + lane] = o4.w * 0.25f;
        }
    }
}

extern "C" void kernel_launch(void* const* d_in, const int* in_sizes, int n_in,
                              void* d_out, int out_size, void* d_ws, size_t ws_size,
                              hipStream_t stream) {
    const float* x   = (const float*)d_in[0];
    const int*   src = (const int*)d_in[1];
    const int*   dst = (const int*)d_in[2];
    const float* W[3]  = {(const float*)d_in[3], (const float*)d_in[7],  (const float*)d_in[11]};
    const float* al[3] = {(const float*)d_in[4], (const float*)d_in[8],  (const float*)d_in[12]};
    const float* ar[3] = {(const float*)d_in[5], (const float*)d_in[9],  (const float*)d_in[13]};
    const float* bb[3] = {(const float*)d_in[6], (const float*)d_in[10], (const float*)d_in[14]};

    size_t big = (size_t)N_NODES * HD;      // 12.8M elems
    unsigned short* featb = (unsigned short*)d_ws;
    unsigned short* hb1 = featb + big;
    unsigned short* hb2 = hb1 + big;
    unsigned short* el = hb2 + big;          // bf16, N*4
    float* er = (float*)(el + (size_t)NPAD * NHEAD);
    int* deg     = (int*)(er + (size_t)NPAD * NHEAD);   // 4 copies
    int* rowptr  = deg + 4 * NPAD;
    int* cursor  = rowptr + NPAD;
    int* csr_src = cursor + NPAD;           // E ints
    int* bsum    = csr_src + N_EDGES;       // 64 ints
    unsigned short* Wp = (unsigned short*)(bsum + 64);  // 3*128*64*8

    // deg zero (DMA) must precede fused_ph's hist atomics
    hipMemsetAsync(deg, 0, (size_t)4 * NPAD * 4, stream);
    // A: packw ∥ hist  (independent; both read only kernel inputs)
    fused_ph_k<<<PACK_BLKS + HIST_BLKS, 256, 0, stream>>>(W[0], W[1], W[2], Wp, dst, deg);
    // B: gemm0 (needs Wp ✓) ∥ scan1 (needs deg ✓)
    fused_gs_k<<<GEMM_BLKS + NB, 256, 0, stream>>>(x, Wp, al[0], ar[0], featb, el, er,
                                                   deg, rowptr, bsum, N_NODES);
    scan3_k<<<NB, 1024, 0, stream>>>(rowptr, bsum, cursor, NB);
    scatter_k<<<(N_EDGES / 2 + 255) / 256, 256, 0, stream>>>(src, dst, cursor, csr_src);

    int g2grid = (N_NODES + 127) / 128;     // 391
    int agrid = (N_NODES + 3) / 4;

    agg_k<0><<<agrid, 256, 0, stream>>>(rowptr, csr_src, el, er, featb,
                                        nullptr, bb[0], nullptr, hb1);
    gemm2_k<<<g2grid, 256, 0, stream>>>(hb1, Wp + (size_t)1 * 128 * 64 * 8,
                                        al[1], ar[1], featb, el, er, N_NODES);
    agg_k<1><<<agrid, 256, 0, stream>>>(rowptr, csr_src, el, er, featb,
                                        hb1, bb[1], nullptr, hb2);
    gemm2_k<<<g2grid, 256, 0, stream>>>(hb2, Wp + (size_t)2 * 128 * 64 * 8,
                                        al[2], ar[2], featb, el, er, N_NODES);
    agg_k<2><<<agrid, 256, 0, stream>>>(rowptr, csr_src, el, er, featb,
                                        hb2, bb[2], (float*)d_out, nullptr);
}

// Round 14
// 296.923 us; speedup vs baseline: 1.1272x; 1.1272x over previous
//
#include <hip/hip_runtime.h>
#include <math.h>

#define N_NODES 50000
#define N_EDGES 800000
#define HD 256      // H*D
#define NHEAD 4
#define DH 64
#define NPAD 50048

#define GEMM_BLKS 782   // ceil(50000/64)
#define PACK_BLKS 96    // 384 tiles / 4 waves
#define EDGE_BLKS 1563  // ceil(800000/2/256)
#define NB 49           // ceil(50000/1024)

typedef short bf16x8 __attribute__((ext_vector_type(8)));
typedef float f32x4 __attribute__((ext_vector_type(4)));

__device__ __forceinline__ unsigned short f2bf(float f) {  // RNE
    unsigned u = __float_as_uint(f);
    return (unsigned short)((u + 0x7fffu + ((u >> 16) & 1u)) >> 16);
}
__device__ __forceinline__ float bf2f(unsigned short h) {
    return __uint_as_float((unsigned)h << 16);
}
// π: stored col c' holds original col orig(c') = (c'&~63) | ((c'&3)*16 + ((c'>>2)&15))
__device__ __forceinline__ int origk(int k) {
    return (k & ~63) | ((k & 3) * 16 + ((k >> 2) & 15));
}

// ---------- shared GEMM pieces ----------
__device__ __forceinline__ void mfma_tile(const unsigned short* Asl,
                                          const unsigned short* wbase,
                                          int lane, f32x4 acc[4][4]) {
#pragma unroll
    for (int kk = 0; kk < 8; kk++) {
        bf16x8 a[4], b[4];
#pragma unroll
        for (int m = 0; m < 4; m++) {
            int r = m * 16 + (lane & 15);
            int kb = kk * 32 + (lane >> 4) * 8;
            int byt = (r * 512 + kb * 2) ^ ((r & 7) << 4);
            a[m] = *(const bf16x8*)((const char*)Asl + byt);
        }
#pragma unroll
        for (int n = 0; n < 4; n++)
            b[n] = *(const bf16x8*)(wbase + ((size_t)(n * 8 + kk) * 64 + lane) * 8);
#pragma unroll
        for (int m = 0; m < 4; m++)
#pragma unroll
            for (int n = 0; n < 4; n++)
                acc[m][n] = __builtin_amdgcn_mfma_f32_16x16x32_bf16(a[m], b[n],
                                                                    acc[m][n], 0, 0, 0);
    }
}

// el/er butterfly + π-layout C store (el bf16, er fp32)
__device__ __forceinline__ void epilogue_tile(f32x4 acc[4][4], int bm, int wv, int lane,
                                              const float* __restrict__ al,
                                              const float* __restrict__ ar,
                                              unsigned short* __restrict__ C,
                                              unsigned short* __restrict__ el,
                                              float* __restrict__ er, int M) {
    int rr = lane >> 4, cc = lane & 15;
    float alv[4], arv[4];
#pragma unroll
    for (int n = 0; n < 4; n++) {
        alv[n] = al[wv * 64 + n * 16 + cc];
        arv[n] = ar[wv * 64 + n * 16 + cc];
    }
    float vl[16], vr[16];
#pragma unroll
    for (int m = 0; m < 4; m++)
#pragma unroll
        for (int r = 0; r < 4; r++) {
            float ep = 0.f, rp = 0.f;
#pragma unroll
            for (int n = 0; n < 4; n++) {
                ep = fmaf(acc[m][n][r], alv[n], ep);
                rp = fmaf(acc[m][n][r], arv[n], rp);
            }
            vl[m * 4 + r] = ep;
            vr[m * 4 + r] = rp;
        }
    float l8[8], r8[8];
#pragma unroll
    for (int i = 0; i < 8; i++) {
        float xs = (cc & 1) ? vl[2 * i] : vl[2 * i + 1];
        float xk = (cc & 1) ? vl[2 * i + 1] : vl[2 * i];
        l8[i] = xk + __shfl_xor(xs, 1);
        float ys = (cc & 1) ? vr[2 * i] : vr[2 * i + 1];
        float yk = (cc & 1) ? vr[2 * i + 1] : vr[2 * i];
        r8[i] = yk + __shfl_xor(ys, 1);
    }
    float l4[4], r4[4];
#pragma unroll
    for (int i = 0; i < 4; i++) {
        float xs = (cc & 2) ? l8[2 * i] : l8[2 * i + 1];
        float xk = (cc & 2) ? l8[2 * i + 1] : l8[2 * i];
        l4[i] = xk + __shfl_xor(xs, 2);
        float ys = (cc & 2) ? r8[2 * i] : r8[2 * i + 1];
        float yk = (cc & 2) ? r8[2 * i + 1] : r8[2 * i];
        r4[i] = yk + __shfl_xor(ys, 2);
    }
    float l2[2], r2[2];
#pragma unroll
    for (int i = 0; i < 2; i++) {
        float xs = (cc & 4) ? l4[2 * i] : l4[2 * i + 1];
        float xk = (cc & 4) ? l4[2 * i + 1] : l4[2 * i];
        l2[i] = xk + __shfl_xor(xs, 4);
        float ys = (cc & 4) ? r4[2 * i] : r4[2 * i + 1];
        float yk = (cc & 4) ? r4[2 * i + 1] : r4[2 * i];
        r2[i] = yk + __shfl_xor(ys, 4);
    }
    {
        float xs = (cc & 8) ? l2[0] : l2[1];
        float xk = (cc & 8) ? l2[1] : l2[0];
        float lv = xk + __shfl_xor(xs, 8);
        float ys = (cc & 8) ? r2[0] : r2[1];
        float yk = (cc & 8) ? r2[1] : r2[0];
        float rv = yk + __shfl_xor(ys, 8);
        int row_e = bm + (cc >> 2) * 16 + rr * 4 + (cc & 3);
        if (row_e < M) {
            el[(size_t)row_e * NHEAD + wv] = f2bf(lv);
            er[(size_t)row_e * NHEAD + wv] = rv;
        }
    }
#pragma unroll
    for (int m = 0; m < 4; m++) {
#pragma unroll
        for (int r = 0; r < 4; r++) {
            int row = bm + m * 16 + rr * 4 + r;
            if (row < M) {
                unsigned short p4[4] = {f2bf(acc[m][0][r]), f2bf(acc[m][1][r]),
                                        f2bf(acc[m][2][r]), f2bf(acc[m][3][r])};
                *(ushort4*)(C + (size_t)row * 256 + wv * 64 + cc * 4) = *(ushort4*)p4;
            }
        }
    }
}

// ---------- dispatch A: packw ∥ hist(+rank) ----------
// rank[e] = this edge's ticket within its (copy, dst) bucket; copy = tid&3.
__global__ __launch_bounds__(256) void fused_ph_k(const float* __restrict__ W0,
                                                  const float* __restrict__ W1,
                                                  const float* __restrict__ W2,
                                                  unsigned short* __restrict__ Wp,
                                                  const int* __restrict__ dst,
                                                  int* __restrict__ deg,
                                                  int* __restrict__ rank) {
    int blk = blockIdx.x, tid = threadIdx.x, wv = tid >> 6, lane = tid & 63;
    if (blk < PACK_BLKS) {
        int tile = blk * 4 + wv;   // 0..383
        int L = tile >> 7, t = tile & 127;
        const float* W = L == 0 ? W0 : L == 1 ? W1 : W2;
        int nt = t >> 3, kt = t & 7;
        int col = nt * 16 + (lane & 15);
        int kb = kt * 32 + (lane >> 4) * 8;
        unsigned short v[8];
#pragma unroll
        for (int j = 0; j < 8; j++) {
            int k = kb + j;
            if (L > 0) k = origk(k);
            v[j] = f2bf(W[(size_t)k * 256 + col]);
        }
        *(bf16x8*)(Wp + ((size_t)(L * 128 + t) * 64 + lane) * 8) = *(bf16x8*)v;
    } else {
        int t = (blk - PACK_BLKS) * 256 + tid;
        int e = t * 2;
        int* mydeg = deg + (size_t)(tid & 3) * NPAD;
        if (e + 1 < N_EDGES) {
            int2 d2 = *(const int2*)(dst + e);
            int r0 = atomicAdd(&mydeg[d2.x], 1);
            int r1 = atomicAdd(&mydeg[d2.y], 1);
            *(int2*)(rank + e) = make_int2(r0, r1);
        } else if (e < N_EDGES) {
            rank[e] = atomicAdd(&mydeg[dst[e]], 1);
        }
    }
}

// ---------- scan1: rowptr local-inclusive + bsum + per-copy offsets ----------
__global__ __launch_bounds__(256) void scan1_k(const int* __restrict__ deg,
                                               int* __restrict__ rowptr,
                                               int* __restrict__ bsum,
                                               int* __restrict__ cpyoff) {
    __shared__ int wsum2[4];
    int tid = threadIdx.x, lane = tid & 63, wv = tid >> 6;
    int i0 = blockIdx.x * 1024 + tid * 4;
    int v[4], p[4];
#pragma unroll
    for (int j = 0; j < 4; j++) {
        int i = i0 + j;
        if (i < N_NODES) {
            int c0 = deg[i], c1 = deg[i + NPAD];
            int c2 = deg[i + 2 * NPAD], c3 = deg[i + 3 * NPAD];
            v[j] = c0 + c1 + c2 + c3;
            cpyoff[i] = 0;
            cpyoff[i + NPAD] = c0;
            cpyoff[i + 2 * NPAD] = c0 + c1;
            cpyoff[i + 3 * NPAD] = c0 + c1 + c2;
        } else {
            v[j] = 0;
        }
    }
    p[0] = v[0]; p[1] = p[0] + v[1]; p[2] = p[1] + v[2]; p[3] = p[2] + v[3];
    int tot = p[3];
    int sc = tot;
#pragma unroll
    for (int o = 1; o < 64; o <<= 1) {
        int t = __shfl_up(sc, o);
        if (lane >= o) sc += t;
    }
    if (lane == 63) wsum2[wv] = sc;
    __syncthreads();
    int woff = 0;
#pragma unroll
    for (int w = 0; w < 4; w++)
        if (w < wv) woff += wsum2[w];
    int excl = woff + sc - tot;
#pragma unroll
    for (int j = 0; j < 4; j++) {
        int i = i0 + j;
        if (i < N_NODES) rowptr[i + 1] = excl + p[j];
    }
    if (tid == 255) bsum[blockIdx.x] = excl + p[3];
}

// ---------- scan3: finalize rowptr with block offsets ----------
__global__ __launch_bounds__(1024) void scan3_k(int* __restrict__ rowptr,
                                                const int* __restrict__ bsum, int nb) {
    __shared__ int boff_s;
    int tid = threadIdx.x;
    if (tid < 64) {
        int v = (tid < nb) ? bsum[tid] : 0;
        int sc = v;
#pragma unroll
        for (int o = 1; o < 64; o <<= 1) {
            int t = __shfl_up(sc, o);
            if ((tid & 63) >= o) sc += t;
        }
        if (tid == (int)blockIdx.x) boff_s = sc - v;  // exclusive prefix
    }
    __syncthreads();
    int off = boff_s;
    int i = blockIdx.x * 1024 + tid;
    if (blockIdx.x == 0 && tid == 0) rowptr[0] = 0;
    if (i < N_NODES) rowptr[i + 1] += off;
}

// ---------- dispatch D: layer-0 GEMM ∥ atomic-free scatter ----------
__global__ __launch_bounds__(256) void fused_gsc_k(const float* __restrict__ A,
                                                   const unsigned short* __restrict__ Wp,
                                                   const float* __restrict__ al,
                                                   const float* __restrict__ ar,
                                                   unsigned short* __restrict__ C,
                                                   unsigned short* __restrict__ el,
                                                   float* __restrict__ er,
                                                   const int* __restrict__ src,
                                                   const int* __restrict__ dst,
                                                   const int* __restrict__ rank,
                                                   const int* __restrict__ rowptr,
                                                   const int* __restrict__ cpyoff,
                                                   int* __restrict__ csr_src, int M) {
    __shared__ unsigned short Asl[64 * 256];
    int blk = blockIdx.x, tid = threadIdx.x, wv = tid >> 6, lane = tid & 63;
    if (blk < GEMM_BLKS) {
        int bm = blk * 64;
#pragma unroll
        for (int i = 0; i < 8; i++) {
            int chunk = i * 256 + tid;
            int r = chunk >> 5, kc = (chunk & 31) * 8;
            float4 f0, f1;
            if (bm + r < M) {
                const float* p = A + (size_t)(bm + r) * 256 + kc;
                f0 = *(const float4*)p;
                f1 = *(const float4*)(p + 4);
            } else {
                f0 = f1 = make_float4(0.f, 0.f, 0.f, 0.f);
            }
            unsigned short tmp[8] = {f2bf(f0.x), f2bf(f0.y), f2bf(f0.z), f2bf(f0.w),
                                     f2bf(f1.x), f2bf(f1.y), f2bf(f1.z), f2bf(f1.w)};
            int b = (r * 512 + kc * 2) ^ ((r & 7) << 4);
            *(bf16x8*)((char*)Asl + b) = *(bf16x8*)tmp;
        }
        __syncthreads();
        const unsigned short* wbase = Wp + (size_t)(wv * 4) * 8 * 64 * 8;
        f32x4 acc[4][4] = {};
        mfma_tile(Asl, wbase, lane, acc);
        epilogue_tile(acc, bm, wv, lane, al, ar, C, el, er, M);
    } else {
        int t = (blk - GEMM_BLKS) * 256 + tid;
        int e = t * 2;
        const int* myoff = cpyoff + (size_t)(tid & 3) * NPAD;  // same copy as hist
        if (e + 1 < N_EDGES) {
            int2 s2 = *(const int2*)(src + e);
            int2 d2 = *(const int2*)(dst + e);
            int2 r2 = *(const int2*)(rank + e);
            csr_src[rowptr[d2.x] + myoff[d2.x] + r2.x] = s2.x;
            csr_src[rowptr[d2.y] + myoff[d2.y] + r2.y] = s2.y;
        } else if (e < N_EDGES) {
            int d = dst[e];
            csr_src[rowptr[d] + myoff[d] + rank[e]] = src[e];
        }
    }
}

// ---------- layers 1/2 GEMM: bf16 A, 2 tiles/block, async dbuf (counted vmcnt) ----------
__global__ __launch_bounds__(256) void gemm2_k(const unsigned short* __restrict__ A,
                                               const unsigned short* __restrict__ Wp,
                                               const float* __restrict__ al,
                                               const float* __restrict__ ar,
                                               unsigned short* __restrict__ C,
                                               unsigned short* __restrict__ el,
                                               float* __restrict__ er, int M) {
    __shared__ unsigned short Asl[2][64 * 256];   // 64 KB
    int tid = threadIdx.x, wv = tid >> 6, lane = tid & 63;
    int bm0 = blockIdx.x * 128, bm1 = bm0 + 64;
#pragma unroll
    for (int i = 0; i < 8; i++) {
        int chunk = i * 256 + tid;
        int r = chunk >> 5;
        int c16 = (chunk & 31) ^ (r & 7);
        int grow = bm0 + r; if (grow >= M) grow = M - 1;
        __builtin_amdgcn_global_load_lds(
            (const __attribute__((address_space(1))) unsigned int*)
                (A + (size_t)grow * 256 + c16 * 8),
            (__attribute__((address_space(3))) unsigned int*)
                ((char*)Asl[0] + (size_t)chunk * 16),
            16, 0, 0);
    }
#pragma unroll
    for (int i = 0; i < 8; i++) {
        int chunk = i * 256 + tid;
        int r = chunk >> 5;
        int c16 = (chunk & 31) ^ (r & 7);
        int grow = bm1 + r; if (grow >= M) grow = M - 1;
        __builtin_amdgcn_global_load_lds(
            (const __attribute__((address_space(1))) unsigned int*)
                (A + (size_t)grow * 256 + c16 * 8),
            (__attribute__((address_space(3))) unsigned int*)
                ((char*)Asl[1] + (size_t)chunk * 16),
            16, 0, 0);
    }
    asm volatile("s_waitcnt vmcnt(8)" ::: "memory");   // tile0 landed; tile1 in flight
    __builtin_amdgcn_sched_barrier(0);
    __builtin_amdgcn_s_barrier();
    const unsigned short* wbase = Wp + (size_t)(wv * 4) * 8 * 64 * 8;
    f32x4 acc[4][4] = {};
    mfma_tile(Asl[0], wbase, lane, acc);
    asm volatile("s_waitcnt vmcnt(0)" ::: "memory");
    __builtin_amdgcn_sched_barrier(0);
    __builtin_amdgcn_s_barrier();
    epilogue_tile(acc, bm0, wv, lane, al, ar, C, el, er, M);
    f32x4 acc2[4][4] = {};
    mfma_tile(Asl[1], wbase, lane, acc2);
    epilogue_tile(acc2, bm1, wv, lane, al, ar, C, el, er, M);
}

// ---------- fused per-dst softmax (max-free) + gather-aggregate + epilogue ----------
// feat/resid/hb in π layout. el bf16. MODE 0: no resid, ELU; MODE 1: resid, ELU;
// MODE 2: resid, no act, head-mean, fp32 out (unpermuted)
template <int MODE>
__global__ __launch_bounds__(256) void agg_k(const int* __restrict__ rowptr,
                                             const int* __restrict__ csr_src,
                                             const unsigned short* __restrict__ el,
                                             const float* __restrict__ er,
                                             const unsigned short* __restrict__ feat,
                                             const unsigned short* __restrict__ resid,
                                             const float* __restrict__ bias,
                                             float* __restrict__ out,
                                             unsigned short* __restrict__ hb) {
    __shared__ int   ws_s[4][64];       // byte offsets s*512
    __shared__ float ws_w[4][4][68];    // [wave][head][edge], pad 68 de-banks
    int wv = threadIdx.x >> 6, lane = threadIdx.x & 63;
    int node = blockIdx.x * 4 + wv;
    if (node >= N_NODES) return;
    int beg = rowptr[node], end = rowptr[node + 1];
    float4 er4 = *(const float4*)(er + (size_t)node * 4);
    float4 acc0 = make_float4(0.f, 0.f, 0.f, 0.f);
    float4 acc1 = make_float4(0.f, 0.f, 0.f, 0.f);
    float4 den = make_float4(0.f, 0.f, 0.f, 0.f);
    int h = lane >> 4;
    int l8 = lane * 8;
    const char* fb = (const char*)feat;
    for (int base = beg; base < end; base += 64) {
        int j = base + lane;
        int soff = 0;
        float4 w = make_float4(0.f, 0.f, 0.f, 0.f);
        if (j < end) {
            int s = csr_src[j];
            soff = s << 9;              // byte offset of feat row (256 bf16)
            ushort4 l4u = *(const ushort4*)(el + (size_t)s * 4);
            float vx = bf2f(l4u.x) + er4.x; vx = vx > 0.f ? vx : 0.2f * vx;
            float vy = bf2f(l4u.y) + er4.y; vy = vy > 0.f ? vy : 0.2f * vy;
            float vz = bf2f(l4u.z) + er4.z; vz = vz > 0.f ? vz : 0.2f * vz;
            float vw = bf2f(l4u.w) + er4.w; vw = vw > 0.f ? vw : 0.2f * vw;
            // max-free softmax: |v| = O(3), exp cannot overflow fp32
            w.x = expf(vx); w.y = expf(vy); w.z = expf(vz); w.w = expf(vw);
            den.x += w.x; den.y += w.y; den.z += w.z; den.w += w.w;
        }
        ws_s[wv][lane] = soff;          // dummy lanes: soff=0, w=0
        ws_w[wv][0][lane] = w.x;
        ws_w[wv][1][lane] = w.y;
        ws_w[wv][2][lane] = w.z;
        ws_w[wv][3][lane] = w.w;
        __builtin_amdgcn_wave_barrier();
        int cnt = end - base; if (cnt > 64) cnt = 64;
        int cnt4 = (cnt + 3) & ~3;      // zero-padded: no tail loop
        for (int k = 0; k < cnt4; k += 4) {
            int4   so = *(const int4*)&ws_s[wv][k];      // broadcast
            float4 w4 = *(const float4*)&ws_w[wv][h][k];
            ushort4 u0 = *(const ushort4*)(fb + (so.x + l8));
            ushort4 u1 = *(const ushort4*)(fb + (so.y + l8));
            ushort4 u2 = *(const ushort4*)(fb + (so.z + l8));
            ushort4 u3 = *(const ushort4*)(fb + (so.w + l8));
            acc0.x = fmaf(w4.x, bf2f(u0.x), acc0.x);
            acc0.y = fmaf(w4.x, bf2f(u0.y), acc0.y);
            acc0.z = fmaf(w4.x, bf2f(u0.z), acc0.z);
            acc0.w = fmaf(w4.x, bf2f(u0.w), acc0.w);
            acc1.x = fmaf(w4.y, bf2f(u1.x), acc1.x);
            acc1.y = fmaf(w4.y, bf2f(u1.y), acc1.y);
            acc1.z = fmaf(w4.y, bf2f(u1.z), acc1.z);
            acc1.w = fmaf(w4.y, bf2f(u1.w), acc1.w);
            acc0.x = fmaf(w4.z, bf2f(u2.x), acc0.x);
            acc0.y = fmaf(w4.z, bf2f(u2.y), acc0.y);
            acc0.z = fmaf(w4.z, bf2f(u2.z), acc0.z);
            acc0.w = fmaf(w4.z, bf2f(u2.w), acc0.w);
            acc1.x = fmaf(w4.w, bf2f(u3.x), acc1.x);
            acc1.y = fmaf(w4.w, bf2f(u3.y), acc1.y);
            acc1.z = fmaf(w4.w, bf2f(u3.z), acc1.z);
            acc1.w = fmaf(w4.w, bf2f(u3.w), acc1.w);
        }
        __builtin_amdgcn_wave_barrier();
    }
    float4 acc;
    acc.x = acc0.x + acc1.x; acc.y = acc0.y + acc1.y;
    acc.z = acc0.z + acc1.z; acc.w = acc0.w + acc1.w;
#pragma unroll
    for (int o = 1; o < 64; o <<= 1) {
        den.x += __shfl_xor(den.x, o);
        den.y += __shfl_xor(den.y, o);
        den.z += __shfl_xor(den.z, o);
        den.w += __shfl_xor(den.w, o);
    }
    float den_me = h == 0 ? den.x : h == 1 ? den.y : h == 2 ? den.z : den.w;
    float r = den_me > 0.f ? 1.f / den_me : 0.f;
    int cc = lane & 15;
    float4 b4;
    b4.x = bias[h * 64 + 0 * 16 + cc];
    b4.y = bias[h * 64 + 1 * 16 + cc];
    b4.z = bias[h * 64 + 2 * 16 + cc];
    b4.w = bias[h * 64 + 3 * 16 + cc];
    float4 o4;
    o4.x = acc.x * r + b4.x;
    o4.y = acc.y * r + b4.y;
    o4.z = acc.z * r + b4.z;
    o4.w = acc.w * r + b4.w;
    if (MODE >= 1) {
        ushort4 r4 = *(const ushort4*)(resid + (size_t)node * HD + lane * 4);
        o4.x += bf2f(r4.x); o4.y += bf2f(r4.y);
        o4.z += bf2f(r4.z); o4.w += bf2f(r4.w);
    }
    if (MODE <= 1) {
        o4.x = o4.x > 0.f ? o4.x : expm1f(o4.x);
        o4.y = o4.y > 0.f ? o4.y : expm1f(o4.y);
        o4.z = o4.z > 0.f ? o4.z : expm1f(o4.z);
        o4.w = o4.w > 0.f ? o4.w : expm1f(o4.w);
        ushort4 hv;
        hv.x = f2bf(o4.x); hv.y = f2bf(o4.y); hv.z = f2bf(o4.z); hv.w = f2bf(o4.w);
        *(ushort4*)(hb + (size_t)node * HD + lane * 4) = hv;
    } else {
        o4.x += __shfl_xor(o4.x, 16); o4.x += __shfl_xor(o4.x, 32);
        o4.y += __shfl_xor(o4.y, 16); o4.y += __shfl_xor(o4.y, 32);
        o4.z += __shfl_xor(o4.z, 16); o4.z += __shfl_xor(o4.z, 32);
        o4.w += __shfl_xor(o4.w, 16); o4.w += __shfl_xor(o4.w, 32);
        if (lane < 16) {
            float* po = out + (size_t)node * DH;
            po[0 * 16 + lane] = o4.x * 0.25f;
            po[1 * 16 + lane] = o4.y * 0.25f;
            po[2 * 16 + lane] = o4.z * 0.25f;
            po[3 * 16 + lane] = o4.w * 0.25f;
        }
    }
}

extern "C" void kernel_launch(void* const* d_in, const int* in_sizes, int n_in,
                              void* d_out, int out_size, void* d_ws, size_t ws_size,
                              hipStream_t stream) {
    const float* x   = (const float*)d_in[0];
    const int*   src = (const int*)d_in[1];
    const int*   dst = (const int*)d_in[2];
    const float* W[3]  = {(const float*)d_in[3], (const float*)d_in[7],  (const float*)d_in[11]};
    const float* al[3] = {(const float*)d_in[4], (const float*)d_in[8],  (const float*)d_in[12]};
    const float* ar[3] = {(const float*)d_in[5], (const float*)d_in[9],  (const float*)d_in[13]};
    const float* bb[3] = {(const float*)d_in[6], (const float*)d_in[10], (const float*)d_in[14]};

    size_t big = (size_t)N_NODES * HD;      // 12.8M elems
    unsigned short* featb = (unsigned short*)d_ws;
    unsigned short* hb1 = featb + big;
    unsigned short* hb2 = hb1 + big;
    unsigned short* el = hb2 + big;          // bf16, N*4
    float* er = (float*)(el + (size_t)NPAD * NHEAD);
    int* deg     = (int*)(er + (size_t)NPAD * NHEAD);   // 4 copies
    int* cpyoff  = deg + 4 * NPAD;                      // 4 copies
    int* rowptr  = cpyoff + 4 * NPAD;
    int* rank    = rowptr + NPAD;           // E ints
    int* csr_src = rank + N_EDGES;          // E ints
    int* bsum    = csr_src + N_EDGES;       // 64 ints
    unsigned short* Wp = (unsigned short*)(bsum + 64);  // 3*128*64*8

    // deg zero (DMA) must precede fused_ph's hist atomics
    hipMemsetAsync(deg, 0, (size_t)4 * NPAD * 4, stream);
    // A: packw ∥ hist(+rank)
    fused_ph_k<<<PACK_BLKS + EDGE_BLKS, 256, 0, stream>>>(W[0], W[1], W[2], Wp,
                                                          dst, deg, rank);
    // B/C: scan
    scan1_k<<<NB, 256, 0, stream>>>(deg, rowptr, bsum, cpyoff);
    scan3_k<<<NB, 1024, 0, stream>>>(rowptr, bsum, NB);
    // D: gemm0 (needs Wp ✓) ∥ atomic-free scatter (needs rowptr/cpyoff/rank ✓)
    fused_gsc_k<<<GEMM_BLKS + EDGE_BLKS, 256, 0, stream>>>(
        x, Wp, al[0], ar[0], featb, el, er, src, dst, rank, rowptr, cpyoff,
        csr_src, N_NODES);

    int g2grid = (N_NODES + 127) / 128;     // 391
    int agrid = (N_NODES + 3) / 4;

    agg_k<0><<<agrid, 256, 0, stream>>>(rowptr, csr_src, el, er, featb,
                                        nullptr, bb[0], nullptr, hb1);
    gemm2_k<<<g2grid, 256, 0, stream>>>(hb1, Wp + (size_t)1 * 128 * 64 * 8,
                                        al[1], ar[1], featb, el, er, N_NODES);
    agg_k<1><<<agrid, 256, 0, stream>>>(rowptr, csr_src, el, er, featb,
                                        hb1, bb[1], nullptr, hb2);
    gemm2_k<<<g2grid, 256, 0, stream>>>(hb2, Wp + (size_t)2 * 128 * 64 * 8,
                                        al[2], ar[2], featb, el, er, N_NODES);
    agg_k<2><<<agrid, 256, 0, stream>>>(rowptr, csr_src, el, er, featb,
                                        hb2, bb[2], (float*)d_out, nullptr);
}

// Round 15
// 293.944 us; speedup vs baseline: 1.1386x; 1.0101x over previous
//
#include <hip/hip_runtime.h>
#include <math.h>

#define N_NODES 50000
#define N_EDGES 800000
#define HD 256      // H*D
#define NHEAD 4
#define DH 64
#define NPAD 50048

#define GEMM_BLKS 782   // ceil(50000/64)
#define PACK_BLKS 96    // 384 tiles / 4 waves
#define EDGE_BLKS 1563  // ceil(800000/2/256)
#define NB 49           // ceil(50000/1024)

typedef short bf16x8 __attribute__((ext_vector_type(8)));
typedef float f32x4 __attribute__((ext_vector_type(4)));

__device__ __forceinline__ unsigned short f2bf(float f) {  // RNE
    unsigned u = __float_as_uint(f);
    return (unsigned short)((u + 0x7fffu + ((u >> 16) & 1u)) >> 16);
}
__device__ __forceinline__ float bf2f(unsigned short h) {
    return __uint_as_float((unsigned)h << 16);
}
// π: stored col c' holds original col orig(c') = (c'&~63) | ((c'&3)*16 + ((c'>>2)&15))
__device__ __forceinline__ int origk(int k) {
    return (k & ~63) | ((k & 3) * 16 + ((k >> 2) & 15));
}

// ---------- shared GEMM pieces ----------
__device__ __forceinline__ void mfma_tile(const unsigned short* Asl,
                                          const unsigned short* wbase,
                                          int lane, f32x4 acc[4][4]) {
#pragma unroll
    for (int kk = 0; kk < 8; kk++) {
        bf16x8 a[4], b[4];
#pragma unroll
        for (int m = 0; m < 4; m++) {
            int r = m * 16 + (lane & 15);
            int kb = kk * 32 + (lane >> 4) * 8;
            int byt = (r * 512 + kb * 2) ^ ((r & 7) << 4);
            a[m] = *(const bf16x8*)((const char*)Asl + byt);
        }
#pragma unroll
        for (int n = 0; n < 4; n++)
            b[n] = *(const bf16x8*)(wbase + ((size_t)(n * 8 + kk) * 64 + lane) * 8);
#pragma unroll
        for (int m = 0; m < 4; m++)
#pragma unroll
            for (int n = 0; n < 4; n++)
                acc[m][n] = __builtin_amdgcn_mfma_f32_16x16x32_bf16(a[m], b[n],
                                                                    acc[m][n], 0, 0, 0);
    }
}

// el/er butterfly + π-layout C store (el bf16, er fp32)
__device__ __forceinline__ void epilogue_tile(f32x4 acc[4][4], int bm, int wv, int lane,
                                              const float* __restrict__ al,
                                              const float* __restrict__ ar,
                                              unsigned short* __restrict__ C,
                                              unsigned short* __restrict__ el,
                                              float* __restrict__ er, int M) {
    int rr = lane >> 4, cc = lane & 15;
    float alv[4], arv[4];
#pragma unroll
    for (int n = 0; n < 4; n++) {
        alv[n] = al[wv * 64 + n * 16 + cc];
        arv[n] = ar[wv * 64 + n * 16 + cc];
    }
    float vl[16], vr[16];
#pragma unroll
    for (int m = 0; m < 4; m++)
#pragma unroll
        for (int r = 0; r < 4; r++) {
            float ep = 0.f, rp = 0.f;
#pragma unroll
            for (int n = 0; n < 4; n++) {
                ep = fmaf(acc[m][n][r], alv[n], ep);
                rp = fmaf(acc[m][n][r], arv[n], rp);
            }
            vl[m * 4 + r] = ep;
            vr[m * 4 + r] = rp;
        }
    float l8[8], r8[8];
#pragma unroll
    for (int i = 0; i < 8; i++) {
        float xs = (cc & 1) ? vl[2 * i] : vl[2 * i + 1];
        float xk = (cc & 1) ? vl[2 * i + 1] : vl[2 * i];
        l8[i] = xk + __shfl_xor(xs, 1);
        float ys = (cc & 1) ? vr[2 * i] : vr[2 * i + 1];
        float yk = (cc & 1) ? vr[2 * i + 1] : vr[2 * i];
        r8[i] = yk + __shfl_xor(ys, 1);
    }
    float l4[4], r4[4];
#pragma unroll
    for (int i = 0; i < 4; i++) {
        float xs = (cc & 2) ? l8[2 * i] : l8[2 * i + 1];
        float xk = (cc & 2) ? l8[2 * i + 1] : l8[2 * i];
        l4[i] = xk + __shfl_xor(xs, 2);
        float ys = (cc & 2) ? r8[2 * i] : r8[2 * i + 1];
        float yk = (cc & 2) ? r8[2 * i + 1] : r8[2 * i];
        r4[i] = yk + __shfl_xor(ys, 2);
    }
    float l2[2], r2[2];
#pragma unroll
    for (int i = 0; i < 2; i++) {
        float xs = (cc & 4) ? l4[2 * i] : l4[2 * i + 1];
        float xk = (cc & 4) ? l4[2 * i + 1] : l4[2 * i];
        l2[i] = xk + __shfl_xor(xs, 4);
        float ys = (cc & 4) ? r4[2 * i] : r4[2 * i + 1];
        float yk = (cc & 4) ? r4[2 * i + 1] : r4[2 * i];
        r2[i] = yk + __shfl_xor(ys, 4);
    }
    {
        float xs = (cc & 8) ? l2[0] : l2[1];
        float xk = (cc & 8) ? l2[1] : l2[0];
        float lv = xk + __shfl_xor(xs, 8);
        float ys = (cc & 8) ? r2[0] : r2[1];
        float yk = (cc & 8) ? r2[1] : r2[0];
        float rv = yk + __shfl_xor(ys, 8);
        int row_e = bm + (cc >> 2) * 16 + rr * 4 + (cc & 3);
        if (row_e < M) {
            el[(size_t)row_e * NHEAD + wv] = f2bf(lv);
            er[(size_t)row_e * NHEAD + wv] = rv;
        }
    }
#pragma unroll
    for (int m = 0; m < 4; m++) {
#pragma unroll
        for (int r = 0; r < 4; r++) {
            int row = bm + m * 16 + rr * 4 + r;
            if (row < M) {
                unsigned short p4[4] = {f2bf(acc[m][0][r]), f2bf(acc[m][1][r]),
                                        f2bf(acc[m][2][r]), f2bf(acc[m][3][r])};
                *(ushort4*)(C + (size_t)row * 256 + wv * 64 + cc * 4) = *(ushort4*)p4;
            }
        }
    }
}

// ---------- dispatch A: packw ∥ hist(+rank) ----------
// rank[e] = this edge's ticket within its (copy, dst) bucket; copy = tid&3.
__global__ __launch_bounds__(256) void fused_ph_k(const float* __restrict__ W0,
                                                  const float* __restrict__ W1,
                                                  const float* __restrict__ W2,
                                                  unsigned short* __restrict__ Wp,
                                                  const int* __restrict__ dst,
                                                  int* __restrict__ deg,
                                                  int* __restrict__ rank) {
    int blk = blockIdx.x, tid = threadIdx.x, wv = tid >> 6, lane = tid & 63;
    if (blk < PACK_BLKS) {
        int tile = blk * 4 + wv;   // 0..383
        int L = tile >> 7, t = tile & 127;
        const float* W = L == 0 ? W0 : L == 1 ? W1 : W2;
        int nt = t >> 3, kt = t & 7;
        int col = nt * 16 + (lane & 15);
        int kb = kt * 32 + (lane >> 4) * 8;
        unsigned short v[8];
#pragma unroll
        for (int j = 0; j < 8; j++) {
            int k = kb + j;
            if (L > 0) k = origk(k);
            v[j] = f2bf(W[(size_t)k * 256 + col]);
        }
        *(bf16x8*)(Wp + ((size_t)(L * 128 + t) * 64 + lane) * 8) = *(bf16x8*)v;
    } else {
        int t = (blk - PACK_BLKS) * 256 + tid;
        int e = t * 2;
        int* mydeg = deg + (size_t)(tid & 3) * NPAD;
        if (e + 1 < N_EDGES) {
            int2 d2 = *(const int2*)(dst + e);
            int r0 = atomicAdd(&mydeg[d2.x], 1);
            int r1 = atomicAdd(&mydeg[d2.y], 1);
            *(int2*)(rank + e) = make_int2(r0, r1);
        } else if (e < N_EDGES) {
            rank[e] = atomicAdd(&mydeg[dst[e]], 1);
        }
    }
}

// ---------- scan1: local-inclusive rowptr + bsum + per-copy scatter bases ----------
// sbase[copy][i] = (block-local exclusive start of node i) + per-copy offset.
// Final scatter pos = sbase[copy][i] + boff[i>>10] + rank.
__global__ __launch_bounds__(256) void scan1_k(const int* __restrict__ deg,
                                               int* __restrict__ rowptr,
                                               int* __restrict__ bsum,
                                               int* __restrict__ sbase) {
    __shared__ int wsum2[4];
    int tid = threadIdx.x, lane = tid & 63, wv = tid >> 6;
    int i0 = blockIdx.x * 1024 + tid * 4;
    int v[4], p[4], c0s[4], c1s[4], c2s[4];
#pragma unroll
    for (int j = 0; j < 4; j++) {
        int i = i0 + j;
        if (i < N_NODES) {
            int c0 = deg[i], c1 = deg[i + NPAD];
            int c2 = deg[i + 2 * NPAD], c3 = deg[i + 3 * NPAD];
            v[j] = c0 + c1 + c2 + c3;
            c0s[j] = c0; c1s[j] = c1; c2s[j] = c2;
        } else {
            v[j] = 0; c0s[j] = c1s[j] = c2s[j] = 0;
        }
    }
    p[0] = v[0]; p[1] = p[0] + v[1]; p[2] = p[1] + v[2]; p[3] = p[2] + v[3];
    int tot = p[3];
    int sc = tot;
#pragma unroll
    for (int o = 1; o < 64; o <<= 1) {
        int t = __shfl_up(sc, o);
        if (lane >= o) sc += t;
    }
    if (lane == 63) wsum2[wv] = sc;
    __syncthreads();
    int woff = 0;
#pragma unroll
    for (int w = 0; w < 4; w++)
        if (w < wv) woff += wsum2[w];
    int excl = woff + sc - tot;      // block-local exclusive prefix before i0
#pragma unroll
    for (int j = 0; j < 4; j++) {
        int i = i0 + j;
        if (i < N_NODES) {
            int incl = excl + p[j];
            rowptr[i + 1] = incl;                       // local inclusive
            int start = incl - v[j];                    // local exclusive start
            sbase[i] = start;
            sbase[i + NPAD] = start + c0s[j];
            sbase[i + 2 * NPAD] = start + c0s[j] + c1s[j];
            sbase[i + 3 * NPAD] = start + c0s[j] + c1s[j] + c2s[j];
        }
    }
    if (tid == 255) bsum[blockIdx.x] = excl + p[3];
}

// per-block exclusive block-offset scan of bsum (NB<=64), result to LDS int[64]
__device__ __forceinline__ void boff_to_lds(const int* __restrict__ bsum,
                                            int* __restrict__ boffs, int tid) {
    if (tid < 64) {
        int v = (tid < NB) ? bsum[tid] : 0;
        int sc = v;
#pragma unroll
        for (int o = 1; o < 64; o <<= 1) {
            int t = __shfl_up(sc, o);
            if ((tid & 63) >= o) sc += t;
        }
        boffs[tid] = sc - v;   // exclusive prefix
    }
    __syncthreads();
}

// ---------- dispatch C: layer-0 GEMM ∥ atomic-free scatter ∥ rowptr finalize ----------
__global__ __launch_bounds__(256) void fused_gsf_k(const float* __restrict__ A,
                                                   const unsigned short* __restrict__ Wp,
                                                   const float* __restrict__ al,
                                                   const float* __restrict__ ar,
                                                   unsigned short* __restrict__ C,
                                                   unsigned short* __restrict__ el,
                                                   float* __restrict__ er,
                                                   const int* __restrict__ src,
                                                   const int* __restrict__ dst,
                                                   const int* __restrict__ rank,
                                                   int* __restrict__ rowptr,
                                                   const int* __restrict__ sbase,
                                                   const int* __restrict__ bsum,
                                                   int* __restrict__ csr_src, int M) {
    __shared__ unsigned short Asl[64 * 256];
    int blk = blockIdx.x, tid = threadIdx.x, wv = tid >> 6, lane = tid & 63;
    if (blk < GEMM_BLKS) {
        int bm = blk * 64;
#pragma unroll
        for (int i = 0; i < 8; i++) {
            int chunk = i * 256 + tid;
            int r = chunk >> 5, kc = (chunk & 31) * 8;
            float4 f0, f1;
            if (bm + r < M) {
                const float* p = A + (size_t)(bm + r) * 256 + kc;
                f0 = *(const float4*)p;
                f1 = *(const float4*)(p + 4);
            } else {
                f0 = f1 = make_float4(0.f, 0.f, 0.f, 0.f);
            }
            unsigned short tmp[8] = {f2bf(f0.x), f2bf(f0.y), f2bf(f0.z), f2bf(f0.w),
                                     f2bf(f1.x), f2bf(f1.y), f2bf(f1.z), f2bf(f1.w)};
            int b = (r * 512 + kc * 2) ^ ((r & 7) << 4);
            *(bf16x8*)((char*)Asl + b) = *(bf16x8*)tmp;
        }
        __syncthreads();
        const unsigned short* wbase = Wp + (size_t)(wv * 4) * 8 * 64 * 8;
        f32x4 acc[4][4] = {};
        mfma_tile(Asl, wbase, lane, acc);
        epilogue_tile(acc, bm, wv, lane, al, ar, C, el, er, M);
    } else if (blk < GEMM_BLKS + EDGE_BLKS) {
        int* boffs = (int*)Asl;
        boff_to_lds(bsum, boffs, tid);
        int t = (blk - GEMM_BLKS) * 256 + tid;
        int e = t * 2;
        const int* mybase = sbase + (size_t)(tid & 3) * NPAD;  // same copy as hist
        if (e + 1 < N_EDGES) {
            int2 s2 = *(const int2*)(src + e);
            int2 d2 = *(const int2*)(dst + e);
            int2 r2 = *(const int2*)(rank + e);
            csr_src[mybase[d2.x] + boffs[d2.x >> 10] + r2.x] = s2.x;
            csr_src[mybase[d2.y] + boffs[d2.y >> 10] + r2.y] = s2.y;
        } else if (e < N_EDGES) {
            int d = dst[e];
            csr_src[mybase[d] + boffs[d >> 10] + rank[e]] = src[e];
        }
    } else {
        int* boffs = (int*)Asl;
        boff_to_lds(bsum, boffs, tid);
        int sblk = blk - GEMM_BLKS - EDGE_BLKS;   // 0..NB-1
        int off = boffs[sblk];
        int i0 = sblk * 1024 + tid * 4;
        if (sblk == 0 && tid == 0) rowptr[0] = 0;
#pragma unroll
        for (int j = 0; j < 4; j++) {
            int i = i0 + j;
            if (i < N_NODES) rowptr[i + 1] += off;
        }
    }
}

// ---------- layers 1/2 GEMM: bf16 A, 2 tiles/block, async dbuf (counted vmcnt) ----------
__global__ __launch_bounds__(256) void gemm2_k(const unsigned short* __restrict__ A,
                                               const unsigned short* __restrict__ Wp,
                                               const float* __restrict__ al,
                                               const float* __restrict__ ar,
                                               unsigned short* __restrict__ C,
                                               unsigned short* __restrict__ el,
                                               float* __restrict__ er, int M) {
    __shared__ unsigned short Asl[2][64 * 256];   // 64 KB
    int tid = threadIdx.x, wv = tid >> 6, lane = tid & 63;
    int bm0 = blockIdx.x * 128, bm1 = bm0 + 64;
#pragma unroll
    for (int i = 0; i < 8; i++) {
        int chunk = i * 256 + tid;
        int r = chunk >> 5;
        int c16 = (chunk & 31) ^ (r & 7);
        int grow = bm0 + r; if (grow >= M) grow = M - 1;
        __builtin_amdgcn_global_load_lds(
            (const __attribute__((address_space(1))) unsigned int*)
                (A + (size_t)grow * 256 + c16 * 8),
            (__attribute__((address_space(3))) unsigned int*)
                ((char*)Asl[0] + (size_t)chunk * 16),
            16, 0, 0);
    }
#pragma unroll
    for (int i = 0; i < 8; i++) {
        int chunk = i * 256 + tid;
        int r = chunk >> 5;
        int c16 = (chunk & 31) ^ (r & 7);
        int grow = bm1 + r; if (grow >= M) grow = M - 1;
        __builtin_amdgcn_global_load_lds(
            (const __attribute__((address_space(1))) unsigned int*)
                (A + (size_t)grow * 256 + c16 * 8),
            (__attribute__((address_space(3))) unsigned int*)
                ((char*)Asl[1] + (size_t)chunk * 16),
            16, 0, 0);
    }
    asm volatile("s_waitcnt vmcnt(8)" ::: "memory");   // tile0 landed; tile1 in flight
    __builtin_amdgcn_sched_barrier(0);
    __builtin_amdgcn_s_barrier();
    const unsigned short* wbase = Wp + (size_t)(wv * 4) * 8 * 64 * 8;
    f32x4 acc[4][4] = {};
    mfma_tile(Asl[0], wbase, lane, acc);
    asm volatile("s_waitcnt vmcnt(0)" ::: "memory");
    __builtin_amdgcn_sched_barrier(0);
    __builtin_amdgcn_s_barrier();
    epilogue_tile(acc, bm0, wv, lane, al, ar, C, el, er, M);
    f32x4 acc2[4][4] = {};
    mfma_tile(Asl[1], wbase, lane, acc2);
    epilogue_tile(acc2, bm1, wv, lane, al, ar, C, el, er, M);
}

// ---------- fused per-dst softmax (max-free) + gather-aggregate + epilogue ----------
// feat/resid/hb in π layout. el bf16. MODE 0: no resid, ELU; MODE 1: resid, ELU;
// MODE 2: resid, no act, head-mean, fp32 out (unpermuted)
template <int MODE>
__global__ __launch_bounds__(256) void agg_k(const int* __restrict__ rowptr,
                                             const int* __restrict__ csr_src,
                                             const unsigned short* __restrict__ el,
                                             const float* __restrict__ er,
                                             const unsigned short* __restrict__ feat,
                                             const unsigned short* __restrict__ resid,
                                             const float* __restrict__ bias,
                                             float* __restrict__ out,
                                             unsigned short* __restrict__ hb) {
    __shared__ int   ws_s[4][64];       // byte offsets s*512
    __shared__ float ws_w[4][4][68];    // [wave][head][edge], pad 68 de-banks
    int wv = threadIdx.x >> 6, lane = threadIdx.x & 63;
    int node = blockIdx.x * 4 + wv;
    if (node >= N_NODES) return;
    int beg = rowptr[node], end = rowptr[node + 1];
    float4 er4 = *(const float4*)(er + (size_t)node * 4);
    float4 acc0 = make_float4(0.f, 0.f, 0.f, 0.f);
    float4 acc1 = make_float4(0.f, 0.f, 0.f, 0.f);
    float4 den = make_float4(0.f, 0.f, 0.f, 0.f);
    int h = lane >> 4;
    int l8 = lane * 8;
    const char* fb = (const char*)feat;
    for (int base = beg; base < end; base += 64) {
        int j = base + lane;
        int soff = 0;
        float4 w = make_float4(0.f, 0.f, 0.f, 0.f);
        if (j < end) {
            int s = csr_src[j];
            soff = s << 9;              // byte offset of feat row (256 bf16)
            ushort4 l4u = *(const ushort4*)(el + (size_t)s * 4);
            float vx = bf2f(l4u.x) + er4.x; vx = vx > 0.f ? vx : 0.2f * vx;
            float vy = bf2f(l4u.y) + er4.y; vy = vy > 0.f ? vy : 0.2f * vy;
            float vz = bf2f(l4u.z) + er4.z; vz = vz > 0.f ? vz : 0.2f * vz;
            float vw = bf2f(l4u.w) + er4.w; vw = vw > 0.f ? vw : 0.2f * vw;
            // max-free softmax: |v| = O(3), exp cannot overflow fp32
            w.x = expf(vx); w.y = expf(vy); w.z = expf(vz); w.w = expf(vw);
            den.x += w.x; den.y += w.y; den.z += w.z; den.w += w.w;
        }
        ws_s[wv][lane] = soff;          // dummy lanes: soff=0, w=0
        ws_w[wv][0][lane] = w.x;
        ws_w[wv][1][lane] = w.y;
        ws_w[wv][2][lane] = w.z;
        ws_w[wv][3][lane] = w.w;
        __builtin_amdgcn_wave_barrier();
        int cnt = end - base; if (cnt > 64) cnt = 64;
        int cnt4 = (cnt + 3) & ~3;      // zero-padded: no tail loop
        for (int k = 0; k < cnt4; k += 4) {
            int4   so = *(const int4*)&ws_s[wv][k];      // broadcast
            float4 w4 = *(const float4*)&ws_w[wv][h][k];
            ushort4 u0 = *(const ushort4*)(fb + (so.x + l8));
            ushort4 u1 = *(const ushort4*)(fb + (so.y + l8));
            ushort4 u2 = *(const ushort4*)(fb + (so.z + l8));
            ushort4 u3 = *(const ushort4*)(fb + (so.w + l8));
            acc0.x = fmaf(w4.x, bf2f(u0.x), acc0.x);
            acc0.y = fmaf(w4.x, bf2f(u0.y), acc0.y);
            acc0.z = fmaf(w4.x, bf2f(u0.z), acc0.z);
            acc0.w = fmaf(w4.x, bf2f(u0.w), acc0.w);
            acc1.x = fmaf(w4.y, bf2f(u1.x), acc1.x);
            acc1.y = fmaf(w4.y, bf2f(u1.y), acc1.y);
            acc1.z = fmaf(w4.y, bf2f(u1.z), acc1.z);
            acc1.w = fmaf(w4.y, bf2f(u1.w), acc1.w);
            acc0.x = fmaf(w4.z, bf2f(u2.x), acc0.x);
            acc0.y = fmaf(w4.z, bf2f(u2.y), acc0.y);
            acc0.z = fmaf(w4.z, bf2f(u2.z), acc0.z);
            acc0.w = fmaf(w4.z, bf2f(u2.w), acc0.w);
            acc1.x = fmaf(w4.w, bf2f(u3.x), acc1.x);
            acc1.y = fmaf(w4.w, bf2f(u3.y), acc1.y);
            acc1.z = fmaf(w4.w, bf2f(u3.z), acc1.z);
            acc1.w = fmaf(w4.w, bf2f(u3.w), acc1.w);
        }
        __builtin_amdgcn_wave_barrier();
    }
    float4 acc;
    acc.x = acc0.x + acc1.x; acc.y = acc0.y + acc1.y;
    acc.z = acc0.z + acc1.z; acc.w = acc0.w + acc1.w;
#pragma unroll
    for (int o = 1; o < 64; o <<= 1) {
        den.x += __shfl_xor(den.x, o);
        den.y += __shfl_xor(den.y, o);
        den.z += __shfl_xor(den.z, o);
        den.w += __shfl_xor(den.w, o);
    }
    float den_me = h == 0 ? den.x : h == 1 ? den.y : h == 2 ? den.z : den.w;
    float r = den_me > 0.f ? 1.f / den_me : 0.f;
    int cc = lane & 15;
    float4 b4;
    b4.x = bias[h * 64 + 0 * 16 + cc];
    b4.y = bias[h * 64 + 1 * 16 + cc];
    b4.z = bias[h * 64 + 2 * 16 + cc];
    b4.w = bias[h * 64 + 3 * 16 + cc];
    float4 o4;
    o4.x = acc.x * r + b4.x;
    o4.y = acc.y * r + b4.y;
    o4.z = acc.z * r + b4.z;
    o4.w = acc.w * r + b4.w;
    if (MODE >= 1) {
        ushort4 r4 = *(const ushort4*)(resid + (size_t)node * HD + lane * 4);
        o4.x += bf2f(r4.x); o4.y += bf2f(r4.y);
        o4.z += bf2f(r4.z); o4.w += bf2f(r4.w);
    }
    if (MODE <= 1) {
        o4.x = o4.x > 0.f ? o4.x : expm1f(o4.x);
        o4.y = o4.y > 0.f ? o4.y : expm1f(o4.y);
        o4.z = o4.z > 0.f ? o4.z : expm1f(o4.z);
        o4.w = o4.w > 0.f ? o4.w : expm1f(o4.w);
        ushort4 hv;
        hv.x = f2bf(o4.x); hv.y = f2bf(o4.y); hv.z = f2bf(o4.z); hv.w = f2bf(o4.w);
        *(ushort4*)(hb + (size_t)node * HD + lane * 4) = hv;
    } else {
        o4.x += __shfl_xor(o4.x, 16); o4.x += __shfl_xor(o4.x, 32);
        o4.y += __shfl_xor(o4.y, 16); o4.y += __shfl_xor(o4.y, 32);
        o4.z += __shfl_xor(o4.z, 16); o4.z += __shfl_xor(o4.z, 32);
        o4.w += __shfl_xor(o4.w, 16); o4.w += __shfl_xor(o4.w, 32);
        if (lane < 16) {
            float* po = out + (size_t)node * DH;
            po[0 * 16 + lane] = o4.x * 0.25f;
            po[1 * 16 + lane] = o4.y * 0.25f;
            po[2 * 16 + lane] = o4.z * 0.25f;
            po[3 * 16 + lane] = o4.w * 0.25f;
        }
    }
}

extern "C" void kernel_launch(void* const* d_in, const int* in_sizes, int n_in,
                              void* d_out, int out_size, void* d_ws, size_t ws_size,
                              hipStream_t stream) {
    const float* x   = (const float*)d_in[0];
    const int*   src = (const int*)d_in[1];
    const int*   dst = (const int*)d_in[2];
    const float* W[3]  = {(const float*)d_in[3], (const float*)d_in[7],  (const float*)d_in[11]};
    const float* al[3] = {(const float*)d_in[4], (const float*)d_in[8],  (const float*)d_in[12]};
    const float* ar[3] = {(const float*)d_in[5], (const float*)d_in[9],  (const float*)d_in[13]};
    const float* bb[3] = {(const float*)d_in[6], (const float*)d_in[10], (const float*)d_in[14]};

    size_t big = (size_t)N_NODES * HD;      // 12.8M elems
    unsigned short* featb = (unsigned short*)d_ws;
    unsigned short* hb1 = featb + big;
    unsigned short* hb2 = hb1 + big;
    unsigned short* el = hb2 + big;          // bf16, N*4
    float* er = (float*)(el + (size_t)NPAD * NHEAD);
    int* deg     = (int*)(er + (size_t)NPAD * NHEAD);   // 4 copies
    int* sbase   = deg + 4 * NPAD;                      // 4 copies
    int* rowptr  = sbase + 4 * NPAD;
    int* rank    = rowptr + NPAD;           // E ints
    int* csr_src = rank + N_EDGES;          // E ints
    int* bsum    = csr_src + N_EDGES;       // 64 ints
    unsigned short* Wp = (unsigned short*)(bsum + 64);  // 3*128*64*8

    // deg zero (DMA) must precede fused_ph's hist atomics
    hipMemsetAsync(deg, 0, (size_t)4 * NPAD * 4, stream);
    // A: packw ∥ hist(+rank)
    fused_ph_k<<<PACK_BLKS + EDGE_BLKS, 256, 0, stream>>>(W[0], W[1], W[2], Wp,
                                                          dst, deg, rank);
    // B: scan1 (local rowptr + bsum + scatter bases)
    scan1_k<<<NB, 256, 0, stream>>>(deg, rowptr, bsum, sbase);
    // C: gemm0 (needs Wp ✓) ∥ scatter (needs sbase/bsum/rank ✓) ∥ rowptr finalize
    fused_gsf_k<<<GEMM_BLKS + EDGE_BLKS + NB, 256, 0, stream>>>(
        x, Wp, al[0], ar[0], featb, el, er, src, dst, rank, rowptr, sbase, bsum,
        csr_src, N_NODES);

    int g2grid = (N_NODES + 127) / 128;     // 391
    int agrid = (N_NODES + 3) / 4;

    agg_k<0><<<agrid, 256, 0, stream>>>(rowptr, csr_src, el, er, featb,
                                        nullptr, bb[0], nullptr, hb1);
    gemm2_k<<<g2grid, 256, 0, stream>>>(hb1, Wp + (size_t)1 * 128 * 64 * 8,
                                        al[1], ar[1], featb, el, er, N_NODES);
    agg_k<1><<<agrid, 256, 0, stream>>>(rowptr, csr_src, el, er, featb,
                                        hb1, bb[1], nullptr, hb2);
    gemm2_k<<<g2grid, 256, 0, stream>>>(hb2, Wp + (size_t)2 * 128 * 64 * 8,
                                        al[2], ar[2], featb, el, er, N_NODES);
    agg_k<2><<<agrid, 256, 0, stream>>>(rowptr, csr_src, el, er, featb,
                                        hb2, bb[2], (float*)d_out, nullptr);
}